// Round 2
// baseline (18845.598 us; speedup 1.0000x reference)
//
#include <hip/hip_runtime.h>

typedef unsigned short u16;
typedef short bf16x8 __attribute__((ext_vector_type(8)));
typedef float f32x4 __attribute__((ext_vector_type(4)));
typedef u16 u16x4 __attribute__((ext_vector_type(4)));

__device__ __forceinline__ u16 f2bf(float f) {
  union { float f; unsigned u; } v; v.f = f;
  unsigned r = v.u + 0x7fffu + ((v.u >> 16) & 1u);
  return (u16)(r >> 16);
}
__device__ __forceinline__ float bf2f(u16 h) {
  union { unsigned u; float f; } v; v.u = ((unsigned)h) << 16; return v.f;
}
// packed gate index p = gs*128 + gate*32 + j  ->  original row gate*256 + gs*32 + j
__device__ __forceinline__ int perm(int p) {
  return (((p & 127) >> 5) << 8) | ((p >> 7) << 5) | (p & 31);
}
__device__ __forceinline__ float sigf(float x) {
  return __builtin_amdgcn_rcpf(1.f + __expf(-x));
}
__device__ __forceinline__ float tanhf_(float x) {
  return 1.f - 2.f * __builtin_amdgcn_rcpf(__expf(2.f * x) + 1.f);
}
__device__ __forceinline__ void gload_lds16(const void* g, void* l) {
  __builtin_amdgcn_global_load_lds((const __attribute__((address_space(1))) void*)g,
                                   (__attribute__((address_space(3))) void*)l, 16, 0, 0);
}

// ---------------- sentinel (ws too small even for minimum tier) ----------------
__global__ void sentinel(float* out, int n) {
  int i = blockIdx.x * 64 + threadIdx.x;
  if (i < n) out[i] = 1.0e6f;
}

// ---------------- weight prep: convert + gate-permute ----------------
__global__ __launch_bounds__(256) void prep_w(
    const float* __restrict__ Wih0, const float* __restrict__ Whh0,
    const float* __restrict__ bih0, const float* __restrict__ bhh0,
    const float* __restrict__ Wih,  const float* __restrict__ Whh,
    const float* __restrict__ bih,  const float* __restrict__ bhh,
    u16* __restrict__ wih0p, u16* __restrict__ wihp,
    u16* __restrict__ whhp, float* __restrict__ biasp)
{
  int idx = blockIdx.x * 256 + threadIdx.x;
  if (idx < 131072) {                        // wih0p [2][1024][64]
    int j = idx;
    int d = j >> 16, p = (j >> 6) & 1023, k = j & 63;
    wih0p[j] = f2bf(Wih0[((size_t)d * 1024 + perm(p)) * 64 + k]);
  } else if (idx < 2228224) {                // wihp [4][1024][512]
    int j = idx - 131072;
    int ld = j >> 19, p = (j >> 9) & 1023, k = j & 511;
    wihp[j] = f2bf(Wih[((size_t)ld * 1024 + perm(p)) * 512 + k]);
  } else if (idx < 3801088) {                // whhp [6][1024][256]
    int j = idx - 2228224;
    int g = j >> 18, p = (j >> 8) & 1023, k = j & 255;
    int l = g >> 1, d = g & 1;
    float v = (l == 0) ? Whh0[((size_t)d * 1024 + perm(p)) * 256 + k]
                       : Whh[((size_t)((l - 1) * 2 + d) * 1024 + perm(p)) * 256 + k];
    whhp[j] = f2bf(v);
  } else if (idx < 3807232) {                // bias [6][1024]
    int j = idx - 3801088;
    int g = j >> 10, p = j & 1023;
    int l = g >> 1, d = g & 1, pp = perm(p);
    float v = (l == 0) ? (bih0[d * 1024 + pp] + bhh0[d * 1024 + pp])
                       : (bih[((l - 1) * 2 + d) * 1024 + pp] + bhh[((l - 1) * 2 + d) * 1024 + pp]);
    biasp[j] = v;
  }
}

// ---------------- x prep (per batch group) ----------------
__global__ __launch_bounds__(256) void prep_x(
    const float* __restrict__ x, u16* __restrict__ xT, int b0, int lgB)
{
  int idx = blockIdx.x * 256 + threadIdx.x;   // [t][bl][k], total 512*Bg*64
  int k = idx & 63;
  int bl = (idx >> 6) & ((1 << lgB) - 1);
  int t = idx >> (6 + lgB);
  xT[idx] = f2bf(x[((size_t)(b0 + bl) * 512 + t) * 64 + k]);
}

// ---------------- gx GEMM: gx = in @ Wih_packed^T + bias ----------------
// rows m = s'*Bg + bl  (s' chunk-local step, bl batch-local), N = 1024
__global__ __launch_bounds__(256) void gx_gemm(
    const u16* __restrict__ A, int K,
    const u16* __restrict__ W, const float* __restrict__ bias,
    u16* __restrict__ gx, int tb2, int sgn, int lgB)
{
  __shared__ u16 aL[128 * 32];
  __shared__ u16 wL[128 * 32];
  int bid = blockIdx.x;
  int ntile = bid & 7, mtile = bid >> 3;
  int tid = threadIdx.x;
  int lane = tid & 63, wid = tid >> 6;
  int l15 = lane & 15, l4 = lane >> 4;
  int mh = wid >> 1, nh = wid & 1;
  int Bmask = (1 << lgB) - 1;
  f32x4 acc[4][4] = {};
  int nk = K >> 5;
  for (int bk = 0; bk < nk; ++bk) {
    __syncthreads();
    #pragma unroll
    for (int iss = 0; iss < 2; ++iss) {
      int s = iss * 256 + tid;
      int r = s >> 2, g = s & 3;
      int sg = g ^ (r & 3);                    // source pre-swizzle (LDS stays linear)
      int m = mtile * 128 + r;
      int trow = tb2 + sgn * (m >> lgB);
      int bl = m & Bmask;
      gload_lds16(A + (((size_t)trow << lgB) + bl) * K + (bk * 32 + sg * 8),
                  &aL[(size_t)(iss * 256 + wid * 64) * 8]);
      int wn = ntile * 128 + r;
      gload_lds16(W + (size_t)wn * K + (bk * 32 + sg * 8),
                  &wL[(size_t)(iss * 256 + wid * 64) * 8]);
    }
    __syncthreads();
    bf16x8 af[4], bf[4];
    #pragma unroll
    for (int i = 0; i < 4; ++i) {
      int ar = mh * 64 + i * 16 + l15;
      af[i] = *(const bf16x8*)&aL[(ar * 4 + (l4 ^ (ar & 3))) * 8];
      int br = nh * 64 + i * 16 + l15;
      bf[i] = *(const bf16x8*)&wL[(br * 4 + (l4 ^ (br & 3))) * 8];
    }
    #pragma unroll
    for (int i = 0; i < 4; ++i)
      #pragma unroll
      for (int j = 0; j < 4; ++j)
        acc[i][j] = __builtin_amdgcn_mfma_f32_16x16x32_bf16(af[i], bf[j], acc[i][j], 0, 0, 0);
  }
  #pragma unroll
  for (int i = 0; i < 4; ++i) {
    #pragma unroll
    for (int j = 0; j < 4; ++j) {
      int gn = ntile * 128 + nh * 64 + j * 16 + l15;
      float bj = bias[gn];
      #pragma unroll
      for (int r = 0; r < 4; ++r) {
        int gm = mtile * 128 + mh * 64 + i * 16 + l4 * 4 + r;
        gx[(size_t)gm * 1024 + gn] = f2bf(acc[i][j][r] + bj);
      }
    }
  }
}

// ---------------- recurrent kernel: TC steps, both dirs ----------------
// grid 16*NBT: bid = gs*(2*NBT) + d*NBT + bt
__global__ __launch_bounds__(256, 1) void recur(
    const u16* __restrict__ whhL, const u16* __restrict__ gxf, const u16* __restrict__ gxb,
    u16* __restrict__ xsOut, float* __restrict__ cg, int* __restrict__ flags,
    int chunk, int TC, int lgB, int lgNBT)
{
  int bid = blockIdx.x;
  int gs = bid >> (1 + lgNBT);
  int rest = bid & ((2 << lgNBT) - 1);
  int d = rest >> lgNBT;
  int bt = rest & ((1 << lgNBT) - 1);
  int tid = threadIdx.x;
  int lane = tid & 63, w = tid >> 6;
  int l15 = lane & 15, l4 = lane >> 4;

  // Whh slice resident in registers (B-fragments), loaded once
  bf16x8 bfr[2][8];
  {
    const u16* wp = whhL + (size_t)d * 262144 + (size_t)(gs * 128 + w * 32) * 256;
    #pragma unroll
    for (int nt = 0; nt < 2; ++nt)
      #pragma unroll
      for (int kk = 0; kk < 8; ++kk)
        bfr[nt][kk] = *(const bf16x8*)&wp[(size_t)(nt * 16 + l15) * 256 + kk * 32 + l4 * 8];
  }

  int q0 = tid * 4;
  int bloc = q0 >> 5, hc0 = q0 & 31;
  int bglob = bt * 32 + bloc;
  float creg[4];
  if (chunk == 0) {
    creg[0] = 0.f; creg[1] = 0.f; creg[2] = 0.f; creg[3] = 0.f;
  } else {
    const float* cp = cg + (((size_t)d << lgB) + bglob) * 256 + gs * 32 + hc0;
    creg[0] = cp[0]; creg[1] = cp[1]; creg[2] = cp[2]; creg[3] = cp[3];
  }

  __shared__ float zl[32][132];
  int tbase = chunk * TC;
  int flgBase = (d * (1 << lgNBT) + bt) * 8;
  const u16* gxp = d ? gxb : gxf;

  for (int s = 0; s < TC; ++s) {
    int t  = d ? (511 - tbase - s) : (tbase + s);
    int tp = d ? (t + 1) : (t - 1);
    bool first = (chunk == 0 && s == 0);

    // prefetch gx into registers (independent of the flag wait / cache inv)
    float gxv[2][2][4];
    #pragma unroll
    for (int mt = 0; mt < 2; ++mt)
      #pragma unroll
      for (int nt = 0; nt < 2; ++nt) {
        int col = gs * 128 + w * 32 + nt * 16 + l15;
        #pragma unroll
        for (int r = 0; r < 4; ++r) {
          int row = bt * 32 + mt * 16 + l4 * 4 + r;
          gxv[mt][nt][r] = bf2f(gxp[(((size_t)s << lgB) + row) * 1024 + col]);
        }
      }

    if (s > 0) {
      if (tid < 8)
        while (__hip_atomic_load(&flags[flgBase + tid], __ATOMIC_RELAXED,
                                 __HIP_MEMORY_SCOPE_AGENT) < s) {}
      __syncthreads();
      // make peers' agent-scope h stores visible to our plain vector loads
      __builtin_amdgcn_fence(__ATOMIC_ACQUIRE, "agent");
    }

    f32x4 acc[2][2] = {};
    if (!first) {
      const u16* hp = xsOut + (((size_t)tp << lgB) + bt * 32) * 512 + d * 256;
      bf16x8 afr[2][8];
      #pragma unroll
      for (int mt = 0; mt < 2; ++mt)
        #pragma unroll
        for (int kk = 0; kk < 8; ++kk)
          afr[mt][kk] = *(const bf16x8*)&hp[(size_t)(mt * 16 + l15) * 512 + kk * 32 + l4 * 8];
      #pragma unroll
      for (int kk = 0; kk < 8; ++kk)
        #pragma unroll
        for (int mt = 0; mt < 2; ++mt)
          #pragma unroll
          for (int nt = 0; nt < 2; ++nt)
            acc[mt][nt] = __builtin_amdgcn_mfma_f32_16x16x32_bf16(afr[mt][kk], bfr[nt][kk], acc[mt][nt], 0, 0, 0);
    }

    #pragma unroll
    for (int mt = 0; mt < 2; ++mt)
      #pragma unroll
      for (int nt = 0; nt < 2; ++nt)
        #pragma unroll
        for (int r = 0; r < 4; ++r)
          zl[mt * 16 + l4 * 4 + r][w * 32 + nt * 16 + l15] = acc[mt][nt][r] + gxv[mt][nt][r];
    __syncthreads();

    f32x4 vi = *(const f32x4*)&zl[bloc][hc0];
    f32x4 vf = *(const f32x4*)&zl[bloc][32 + hc0];
    f32x4 vg = *(const f32x4*)&zl[bloc][64 + hc0];
    f32x4 vo = *(const f32x4*)&zl[bloc][96 + hc0];
    float hnew[4];
    #pragma unroll
    for (int j = 0; j < 4; ++j) {
      float c = sigf(vf[j]) * creg[j] + sigf(vi[j]) * tanhf_(vg[j]);
      creg[j] = c;
      hnew[j] = sigf(vo[j]) * tanhf_(c);
    }
    // agent-scope (write-through) stores so peer blocks on other XCDs see h
    {
      size_t ho = (((size_t)t << lgB) + bglob) * 512 + d * 256 + gs * 32 + hc0;
      unsigned lo = (unsigned)f2bf(hnew[0]) | ((unsigned)f2bf(hnew[1]) << 16);
      unsigned hi = (unsigned)f2bf(hnew[2]) | ((unsigned)f2bf(hnew[3]) << 16);
      unsigned* dst = (unsigned*)(xsOut + ho);
      __hip_atomic_store(dst, lo, __ATOMIC_RELAXED, __HIP_MEMORY_SCOPE_AGENT);
      __hip_atomic_store(dst + 1, hi, __ATOMIC_RELAXED, __HIP_MEMORY_SCOPE_AGENT);
    }
    if (s == TC - 1) {
      float* cp = cg + (((size_t)d << lgB) + bglob) * 256 + gs * 32 + hc0;
      cp[0] = creg[0]; cp[1] = creg[1]; cp[2] = creg[2]; cp[3] = creg[3];
    }
    __syncthreads();   // drains each wave's vmcnt -> all h stores complete
    if (tid == 0)
      __hip_atomic_store(&flags[flgBase + gs], s + 1, __ATOMIC_RELAXED, __HIP_MEMORY_SCOPE_AGENT);
  }
}

// ---------------- FC head (per batch group) ----------------
__global__ __launch_bounds__(256) void head(
    const u16* __restrict__ xs, const float* __restrict__ w1, const float* __restrict__ b1,
    const float* __restrict__ w2, const float* __restrict__ b2, float* __restrict__ out,
    int b0, int lgB)
{
  int b = blockIdx.x, tid = threadIdx.x;
  __shared__ float hid[512];
  __shared__ float red[4];
  for (int j = tid; j < 512; j += 256) {
    float v = (j < 256) ? bf2f(xs[(((size_t)511 << lgB) + b) * 512 + j])   // hT_f = hs_f[511]
                        : bf2f(xs[((size_t)b) * 512 + j]);                 // hT_b = hs_b[0]
    hid[j] = v;
  }
  __syncthreads();
  float acc = b1[tid];
  const float* wr = w1 + (size_t)tid * 512;
  for (int k = 0; k < 512; ++k) acc = fmaf(hid[k], wr[k], acc);
  float h1 = fmaxf(acc, 0.f);
  float p = h1 * w2[tid];
  #pragma unroll
  for (int off = 32; off > 0; off >>= 1) p += __shfl_down(p, off, 64);
  if ((tid & 63) == 0) red[tid >> 6] = p;
  __syncthreads();
  if (tid == 0) {
    float sum = red[0] + red[1] + red[2] + red[3] + b2[0];
    out[b0 + b] = 1.f / (1.f + __expf(-sum));
  }
}

// ---------------- launcher ----------------
extern "C" void kernel_launch(void* const* d_in, const int* in_sizes, int n_in,
                              void* d_out, int out_size, void* d_ws, size_t ws_size,
                              hipStream_t stream)
{
  const float* x    = (const float*)d_in[0];
  const float* Wih0 = (const float*)d_in[1];
  const float* Whh0 = (const float*)d_in[2];
  const float* bih0 = (const float*)d_in[3];
  const float* bhh0 = (const float*)d_in[4];
  const float* Wih  = (const float*)d_in[5];
  const float* Whh  = (const float*)d_in[6];
  const float* bih  = (const float*)d_in[7];
  const float* bhh  = (const float*)d_in[8];
  const float* fc1w = (const float*)d_in[9];
  const float* fc1b = (const float*)d_in[10];
  const float* fc2w = (const float*)d_in[11];
  const float* fc2b = (const float*)d_in[12];
  float* out = (float*)d_out;

  // ---- adaptive tier selection (Bg = batch group, TC = timestep chunk) ----
  const size_t SZ_WIH0 = 262144, SZ_WIH = 4194304, SZ_WHH = 3145728,
               SZ_BIAS = 24576, SZ_FLAGS = 196608;
  const size_t fixed = SZ_WIH0 + SZ_WIH + SZ_WHH + SZ_BIAS + SZ_FLAGS;
  const int cand[7][2] = {{256,64},{256,32},{256,16},{128,64},{128,32},{64,32},{32,32}};
  int Bg = 0, TC = 0;
  for (int i = 0; i < 7; ++i) {
    size_t bg = cand[i][0], tc = cand[i][1];
    size_t need = fixed + 2048 * bg /*cg*/ + 4096 * tc * bg /*gxf+gxb*/
                + 2 * 524288 * bg /*bufA+bufB (xT aliases bufB)*/;
    if (need <= ws_size) { Bg = cand[i][0]; TC = cand[i][1]; break; }
  }
  if (!Bg) {
    sentinel<<<dim3((out_size + 63) / 64), dim3(64), 0, stream>>>(out, out_size);
    return;
  }
  int lgB = 31 - __builtin_clz((unsigned)Bg);
  int lgNBT = lgB - 5;
  int NBT = Bg >> 5;
  int NC = 512 / TC;
  int NGB = 256 / Bg;

  char* ws = (char*)d_ws;
  size_t off = 0;
  u16* wih0p   = (u16*)(ws + off); off += SZ_WIH0;
  u16* wihp    = (u16*)(ws + off); off += SZ_WIH;
  u16* whhp    = (u16*)(ws + off); off += SZ_WHH;
  float* biasp = (float*)(ws + off); off += SZ_BIAS;
  int* flags   = (int*)(ws + off); off += SZ_FLAGS;
  float* cgb   = (float*)(ws + off); off += 2048 * (size_t)Bg;
  u16* gxf     = (u16*)(ws + off); off += 2048 * (size_t)TC * Bg;
  u16* gxb     = (u16*)(ws + off); off += 2048 * (size_t)TC * Bg;
  u16* bufA    = (u16*)(ws + off); off += 524288 * (size_t)Bg;
  u16* bufB    = (u16*)(ws + off); off += 524288 * (size_t)Bg;
  u16* xT      = bufB;   // alias: xT dead before bufB's first write (layer 1)

  hipMemsetAsync(flags, 0, SZ_FLAGS, stream);
  prep_w<<<dim3(14872), dim3(256), 0, stream>>>(Wih0, Whh0, bih0, bhh0, Wih, Whh, bih, bhh,
                                                wih0p, wihp, whhp, biasp);
  for (int g = 0; g < NGB; ++g) {
    int b0 = g * Bg;
    prep_x<<<dim3(128 * Bg), dim3(256), 0, stream>>>(x, xT, b0, lgB);
    for (int l = 0; l < 3; ++l) {
      const u16* Ain = (l == 0) ? xT : ((l == 1) ? bufA : bufB);
      u16* Bout = (l == 1) ? bufB : bufA;
      int K = l ? 512 : 64;
      int mtiles = (TC * Bg) >> 7;
      for (int c = 0; c < NC; ++c) {
        for (int dct = 0; dct < 2; ++dct) {
          const u16* Wd = (l == 0) ? (wih0p + (size_t)dct * 65536)
                                   : (wihp + (size_t)((l - 1) * 2 + dct) * 524288);
          const float* bd = biasp + (size_t)(l * 2 + dct) * 1024;
          u16* gxd = dct ? gxb : gxf;
          int tb2 = dct ? (511 - c * TC) : (c * TC);
          int sgn = dct ? -1 : 1;
          gx_gemm<<<dim3(mtiles * 8), dim3(256), 0, stream>>>(Ain, K, Wd, bd, gxd, tb2, sgn, lgB);
        }
        int region = (g * 3 + l) * NC + c;
        recur<<<dim3(16 * NBT), dim3(256), 0, stream>>>(whhp + (size_t)l * 524288, gxf, gxb,
                                                        Bout, cgb, flags + region * 128,
                                                        c, TC, lgB, lgNBT);
      }
    }
    head<<<dim3(Bg), dim3(256), 0, stream>>>(bufA, fc1w, fc1b, fc2w, fc2b, out, b0, lgB);
  }
}